// Round 1
// baseline (1071.367 us; speedup 1.0000x reference)
//
#include <hip/hip_runtime.h>

#define TDIM 256
#define VDIM 25
#define CDIM 64
#define BDIM 32
#define SDIM 3
#define TSD 9
#define ODIM 64
#define EPSV 1e-5f

// workspace layout (floats)
#define XM_OFF    0            // 32*64*25 = 51200
#define WBUF_OFF  51200        // 3*32*9*25*32 = 691200 (i padded 25->32)
#define W3T_OFF   742400       // 3*64*64 = 12288
#define LOSSP_OFF 754688       // 1024*3 = 3072
// total 757760 floats = ~3.0 MB

// ---------------- Kernel 1: xm[b,c,v] = mean over T ----------------
__global__ __launch_bounds__(256) void kmean(const float* __restrict__ x,
                                             float* __restrict__ ws) {
  int bc = blockIdx.x;              // 0..2047 (= b*64 + c)
  int tid = threadIdx.x;
  int vl = tid & 31, tr = tid >> 5; // 8 t-rows
  float acc = 0.f;
  if (vl < VDIM) {
    const float* p = x + (size_t)bc * TDIM * VDIM + vl;
    for (int t = tr; t < TDIM; t += 8) acc += p[(size_t)t * VDIM];
  }
  __shared__ float red[256];
  red[tid] = acc;
  __syncthreads();
  if (tr == 0 && vl < VDIM) {
    float s = 0.f;
    for (int r = 0; r < 8; ++r) s += red[r * 32 + vl];
    ws[XM_OFF + bc * VDIM + vl] = s * (1.f / 256.f);
  }
}

// ---------------- Kernel 2: dynamic weights w, ridge, W3^T ----------------
__global__ __launch_bounds__(256) void kadj(const float* __restrict__ A,
                                            const float* __restrict__ alpha,
                                            const float* __restrict__ W1,
                                            const float* __restrict__ b1,
                                            const float* __restrict__ W2,
                                            const float* __restrict__ b2,
                                            const float* __restrict__ W3,
                                            float* __restrict__ ws,
                                            float* __restrict__ out_ridge) {
  int s = blockIdx.x >> 5, b = blockIdx.x & 31;
  int tid = threadIdx.x;
  __shared__ float xm[CDIM * VDIM];
  __shared__ float w1l[TSD * CDIM], w2l[TSD * CDIM];
  __shared__ float b1l[TSD], b2l[TSD];
  __shared__ float x1l[TSD * VDIM], x2l[TSD * VDIM];
  __shared__ float red[256];

  for (int i = tid; i < CDIM * VDIM; i += 256) xm[i] = ws[XM_OFF + b * CDIM * VDIM + i];
  for (int i = tid; i < TSD * CDIM; i += 256) {
    w1l[i] = W1[s * TSD * CDIM + i];
    w2l[i] = W2[s * TSD * CDIM + i];
  }
  if (tid < TSD) { b1l[tid] = b1[s * TSD + tid]; b2l[tid] = b2[s * TSD + tid]; }
  __syncthreads();

  if (tid < TSD * VDIM) {
    int ts = tid / VDIM, v = tid % VDIM;
    float a1 = 0.f, a2 = 0.f;
    for (int c = 0; c < CDIM; ++c) {
      float xv = xm[c * VDIM + v];
      a1 = fmaf(xv, w1l[ts * CDIM + c], a1);
      a2 = fmaf(xv, w2l[ts * CDIM + c], a2);
    }
    x1l[tid] = a1 + b1l[ts];
    x2l[tid] = a2 + b2l[ts];
  }
  __syncthreads();

  float al = alpha[0];
  float rid = 0.f;
  // w[s,b,k,v,i] = tanh(x1[k,v]-x2[k,i])*alpha + A[s,v,i]  (i padded to 32)
  for (int idx = tid; idx < TSD * VDIM * VDIM; idx += 256) {
    int k = idx / (VDIM * VDIM);
    int r = (idx / VDIM) % VDIM;   // v (source, from x1)
    int q = idx % VDIM;            // i (dest, from x2)
    float adj = tanhf(x1l[k * VDIM + r] - x2l[k * VDIM + q]);
    rid += adj * adj;
    float wv = fmaf(adj, al, A[(s * VDIM + r) * VDIM + q]);
    ws[WBUF_OFF + ((((s * BDIM + b) * TSD + k) * VDIM + r) << 5) + q] = wv;
  }
  // zero the i=25..31 pad
  for (int idx = tid; idx < TSD * VDIM * 7; idx += 256) {
    int k = idx / (VDIM * 7), rem = idx % (VDIM * 7);
    int r = rem / 7, q = 25 + rem % 7;
    ws[WBUF_OFF + ((((s * BDIM + b) * TSD + k) * VDIM + r) << 5) + q] = 0.f;
  }

  red[tid] = rid;
  __syncthreads();
  for (int st = 128; st > 0; st >>= 1) {
    if (tid < st) red[tid] += red[tid + st];
    __syncthreads();
  }
  if (tid == 0) out_ridge[s * BDIM + b] = red[0];

  if (b == 0) {  // W3^T: [s][c][o]
    for (int idx = tid; idx < ODIM * CDIM; idx += 256) {
      int o = idx / CDIM, c = idx % CDIM;
      ws[W3T_OFF + (s * CDIM + c) * ODIM + o] = W3[(s * ODIM + o) * CDIM + c];
    }
  }
}

// ---------------- Kernel 3: fused z -> (loss, y=BN(conv3)+x, relu) ----------------
__global__ __launch_bounds__(256) void kmain(const float* __restrict__ x,
                                             const float* __restrict__ b3,
                                             const float* __restrict__ bng,
                                             const float* __restrict__ bnb,
                                             const float* __restrict__ bnm,
                                             const float* __restrict__ bnv,
                                             const float* __restrict__ ws,
                                             float* __restrict__ out,
                                             float* __restrict__ lossP) {
  const int tile = blockIdx.x;   // 0..31  (8 t per tile)
  const int b    = blockIdx.y;   // 0..31
  const int t0   = tile * 8;
  const int tid  = threadIdx.x;
  const int wid  = __builtin_amdgcn_readfirstlane(tid >> 6); // wave id 0..3
  const int lane = tid & 63;
  const int t_l  = lane >> 3, c_l = lane & 7;                // z-phase mapping
  const int i0   = wid * 8;                                  // i-group

  __shared__ float xw[16 * 25 * 8];                 // [t'16][v25][c8]
  __shared__ __align__(16) float zl[8 * 8 * 36];    // [c8][t8][i32 pad36]

  const int op = tid & 31;   // y-phase: owns o=op and o=op+32
  const int tq = tid >> 5;   // y-phase: t

  float acc0[32], acc1[32];
#pragma unroll
  for (int i = 0; i < 32; ++i) { acc0[i] = 0.f; acc1[i] = 0.f; }
  float loss0 = 0.f, loss1 = 0.f, loss2 = 0.f;

  const float4* wb4 = (const float4*)(ws + WBUF_OFF);
  const float* w3t = ws + W3T_OFF;

  const int svl = tid & 31, scc = tid >> 5;  // staging mapping

  for (int oct = 0; oct < 8; ++oct) {
    // stage x window: xw[t'][v][cc] = x[b, oct*8+cc, t0-8+t', v]
    if (svl < VDIM) {
      const float* xsrc = x + (size_t)(b * 64 + oct * 8 + scc) * TDIM * VDIM + svl;
#pragma unroll
      for (int tp = 0; tp < 16; ++tp) {
        int gt = t0 - 8 + tp;
        xw[tp * 200 + svl * 8 + scc] = (gt >= 0) ? xsrc[(size_t)gt * VDIM] : 0.f;
      }
    }
    __syncthreads();

#pragma unroll
    for (int s = 0; s < 3; ++s) {
      // ---- z-phase: wave computes 8 i's for lanes (t_l, c_l) ----
      float z[8];
#pragma unroll
      for (int j = 0; j < 8; ++j) z[j] = 0.f;
      const int wbase0 = ((s * BDIM + b) * TSD * VDIM) * 8 + (i0 >> 2); // float4 units
      for (int v = 0; v < VDIM; ++v) {
        float xv[9];
#pragma unroll
        for (int k = 0; k < 9; ++k)
          xv[k] = xw[(t_l + k) * 200 + v * 8 + c_l];
#pragma unroll
        for (int k = 0; k < 9; ++k) {
          float4 wa = wb4[wbase0 + (k * VDIM + v) * 8];
          float4 wbv = wb4[wbase0 + (k * VDIM + v) * 8 + 1];
          z[0] = fmaf(xv[k], wa.x, z[0]);
          z[1] = fmaf(xv[k], wa.y, z[1]);
          z[2] = fmaf(xv[k], wa.z, z[2]);
          z[3] = fmaf(xv[k], wa.w, z[3]);
          z[4] = fmaf(xv[k], wbv.x, z[4]);
          z[5] = fmaf(xv[k], wbv.y, z[5]);
          z[6] = fmaf(xv[k], wbv.z, z[6]);
          z[7] = fmaf(xv[k], wbv.w, z[7]);
        }
      }
      // loss partial: (z - x[b,c,t0+t_l,i])^2, i<25 only
      {
        float lp = 0.f;
#pragma unroll
        for (int j = 0; j < 8; ++j) {
          if (i0 + j < VDIM) {
            float xval = xw[(t_l + 8) * 200 + (i0 + j) * 8 + c_l];
            float d = z[j] - xval;
            lp = fmaf(d, d, lp);
          }
        }
        if (s == 0) loss0 += lp; else if (s == 1) loss1 += lp; else loss2 += lp;
      }
      // hand z to LDS
      {
        float4* zp = (float4*)&zl[(c_l * 8 + t_l) * 36 + i0];
        zp[0] = make_float4(z[0], z[1], z[2], z[3]);
        zp[1] = make_float4(z[4], z[5], z[6], z[7]);
      }
      __syncthreads();
      // ---- y-phase: thread (op, tq) accumulates y[o,t,i] over 8 c's ----
      for (int cc = 0; cc < 8; ++cc) {
        int c = oct * 8 + cc;
        float w3a = w3t[(s * CDIM + c) * ODIM + op];
        float w3b = w3t[(s * CDIM + c) * ODIM + op + 32];
        const float4* zrow = (const float4*)&zl[(cc * 8 + tq) * 36];
#pragma unroll
        for (int i4 = 0; i4 < 8; ++i4) {
          float4 zv = zrow[i4];
          acc0[i4 * 4 + 0] = fmaf(w3a, zv.x, acc0[i4 * 4 + 0]);
          acc0[i4 * 4 + 1] = fmaf(w3a, zv.y, acc0[i4 * 4 + 1]);
          acc0[i4 * 4 + 2] = fmaf(w3a, zv.z, acc0[i4 * 4 + 2]);
          acc0[i4 * 4 + 3] = fmaf(w3a, zv.w, acc0[i4 * 4 + 3]);
          acc1[i4 * 4 + 0] = fmaf(w3b, zv.x, acc1[i4 * 4 + 0]);
          acc1[i4 * 4 + 1] = fmaf(w3b, zv.y, acc1[i4 * 4 + 1]);
          acc1[i4 * 4 + 2] = fmaf(w3b, zv.z, acc1[i4 * 4 + 2]);
          acc1[i4 * 4 + 3] = fmaf(w3b, zv.w, acc1[i4 * 4 + 3]);
        }
      }
      __syncthreads();
    }
  }

  // ---- loss partial reduce -> lossP[block][s] ----
  __shared__ float red[256];
#pragma unroll
  for (int s = 0; s < 3; ++s) {
    float lp = (s == 0) ? loss0 : ((s == 1) ? loss1 : loss2);
    red[tid] = lp;
    __syncthreads();
    for (int st = 128; st > 0; st >>= 1) {
      if (tid < st) red[tid] += red[tid + st];
      __syncthreads();
    }
    if (tid == 0) lossP[(blockIdx.y * 32 + blockIdx.x) * 3 + s] = red[0];
    __syncthreads();
  }

  // ---- epilogue: y = relu(BN(y + b3sum) + x) ----
  float b3s0 = b3[op] + b3[ODIM + op] + b3[2 * ODIM + op];
  float b3s1 = b3[op + 32] + b3[ODIM + op + 32] + b3[2 * ODIM + op + 32];
  float inv0 = bng[op] / sqrtf(bnv[op] + EPSV);
  float inv1 = bng[op + 32] / sqrtf(bnv[op + 32] + EPSV);
  float mu0 = bnm[op], mu1 = bnm[op + 32];
  float be0 = bnb[op], be1 = bnb[op + 32];

  {
    size_t r0 = ((size_t)(b * 64 + op) * TDIM + t0 + tq) * VDIM;
    size_t r1 = ((size_t)(b * 64 + op + 32) * TDIM + t0 + tq) * VDIM;
    const float* xr0 = x + r0;
    const float* xr1 = x + r1;
    float* yo0 = out + r0;
    float* yo1 = out + r1;
#pragma unroll
    for (int i = 0; i < VDIM; ++i) {
      float v0 = (acc0[i] + b3s0 - mu0) * inv0 + be0 + xr0[i];
      float v1 = (acc1[i] + b3s1 - mu1) * inv1 + be1 + xr1[i];
      yo0[i] = fmaxf(v0, 0.f);
      yo1[i] = fmaxf(v1, 0.f);
    }
  }
}

// ---------------- Kernel 4: finalize loss ----------------
__global__ __launch_bounds__(256) void kfin(const float* __restrict__ lossP,
                                            float* __restrict__ out_loss) {
  __shared__ float red[256];
  int tid = threadIdx.x;
  for (int s = 0; s < 3; ++s) {
    float a = 0.f;
    for (int i = tid; i < 1024; i += 256) a += lossP[i * 3 + s];
    red[tid] = a;
    __syncthreads();
    for (int st = 128; st > 0; st >>= 1) {
      if (tid < st) red[tid] += red[tid + st];
      __syncthreads();
    }
    if (tid == 0) out_loss[s] = red[0] * (1.f / 13107200.f);
    __syncthreads();
  }
}

extern "C" void kernel_launch(void* const* d_in, const int* in_sizes, int n_in,
                              void* d_out, int out_size, void* d_ws, size_t ws_size,
                              hipStream_t stream) {
  (void)in_sizes; (void)n_in; (void)out_size; (void)ws_size;
  const float* x     = (const float*)d_in[0];
  const float* A     = (const float*)d_in[1];
  const float* alpha = (const float*)d_in[2];
  const float* W1    = (const float*)d_in[3];
  const float* b1    = (const float*)d_in[4];
  const float* W2    = (const float*)d_in[5];
  const float* b2    = (const float*)d_in[6];
  const float* W3    = (const float*)d_in[7];
  const float* b3    = (const float*)d_in[8];
  const float* bng   = (const float*)d_in[9];
  const float* bnb   = (const float*)d_in[10];
  const float* bnm   = (const float*)d_in[11];
  const float* bnv   = (const float*)d_in[12];
  float* out = (float*)d_out;
  float* ws  = (float*)d_ws;
  float* out_loss  = out + 13107200;
  float* out_ridge = out + 13107203;
  float* lossP = ws + LOSSP_OFF;

  kmean<<<2048, 256, 0, stream>>>(x, ws);
  kadj<<<96, 256, 0, stream>>>(A, alpha, W1, b1, W2, b2, W3, ws, out_ridge);
  kmain<<<dim3(32, 32), 256, 0, stream>>>(x, b3, bng, bnb, bnm, bnv, ws, out, lossP);
  kfin<<<1, 256, 0, stream>>>(lossP, out_loss);
}

// Round 2
// 620.617 us; speedup vs baseline: 1.7263x; 1.7263x over previous
//
#include <hip/hip_runtime.h>

#define TDIM 256
#define VDIM 25
#define CDIM 64
#define BDIM 32
#define SDIM 3
#define TSD 9
#define ODIM 64
#define EPSV 1e-5f

// workspace layout (floats)
#define XM_OFF    0            // 32*64*25 = 51200
#define WBUF_OFF  51200        // 3*32*9*25*25 = 540000  (w[s][b][k][v][i], i dense 25)
#define W3T_OFF   591200       // 3*64*64 = 12288
#define LOSSP_OFF 603488       // 1024*3 = 3072
// total 606560 floats = ~2.43 MB

// ---------------- Kernel 1: xm[b,c,v] = mean over T ----------------
__global__ __launch_bounds__(256) void kmean(const float* __restrict__ x,
                                             float* __restrict__ ws) {
  int bc = blockIdx.x;              // 0..2047 (= b*64 + c)
  int tid = threadIdx.x;
  int vl = tid & 31, tr = tid >> 5; // 8 t-rows
  float acc = 0.f;
  if (vl < VDIM) {
    const float* p = x + (size_t)bc * TDIM * VDIM + vl;
    for (int t = tr; t < TDIM; t += 8) acc += p[(size_t)t * VDIM];
  }
  __shared__ float red[256];
  red[tid] = acc;
  __syncthreads();
  if (tr == 0 && vl < VDIM) {
    float s = 0.f;
    for (int r = 0; r < 8; ++r) s += red[r * 32 + vl];
    ws[XM_OFF + bc * VDIM + vl] = s * (1.f / 256.f);
  }
}

// ---------------- Kernel 2: dynamic weights w, ridge, W3^T ----------------
__global__ __launch_bounds__(256) void kadj(const float* __restrict__ A,
                                            const float* __restrict__ alpha,
                                            const float* __restrict__ W1,
                                            const float* __restrict__ b1,
                                            const float* __restrict__ W2,
                                            const float* __restrict__ b2,
                                            const float* __restrict__ W3,
                                            float* __restrict__ ws,
                                            float* __restrict__ out_ridge) {
  int s = blockIdx.x >> 5, b = blockIdx.x & 31;
  int tid = threadIdx.x;
  __shared__ float xm[CDIM * VDIM];
  __shared__ float w1l[TSD * CDIM], w2l[TSD * CDIM];
  __shared__ float b1l[TSD], b2l[TSD];
  __shared__ float x1l[TSD * VDIM], x2l[TSD * VDIM];
  __shared__ float red[256];

  for (int i = tid; i < CDIM * VDIM; i += 256) xm[i] = ws[XM_OFF + b * CDIM * VDIM + i];
  for (int i = tid; i < TSD * CDIM; i += 256) {
    w1l[i] = W1[s * TSD * CDIM + i];
    w2l[i] = W2[s * TSD * CDIM + i];
  }
  if (tid < TSD) { b1l[tid] = b1[s * TSD + tid]; b2l[tid] = b2[s * TSD + tid]; }
  __syncthreads();

  if (tid < TSD * VDIM) {
    int ts = tid / VDIM, v = tid % VDIM;
    float a1 = 0.f, a2 = 0.f;
    for (int c = 0; c < CDIM; ++c) {
      float xv = xm[c * VDIM + v];
      a1 = fmaf(xv, w1l[ts * CDIM + c], a1);
      a2 = fmaf(xv, w2l[ts * CDIM + c], a2);
    }
    x1l[tid] = a1 + b1l[ts];
    x2l[tid] = a2 + b2l[ts];
  }
  __syncthreads();

  float al = alpha[0];
  float rid = 0.f;
  // w[s,b,k,v,i] = tanh(x1[k,v]-x2[k,i])*alpha + A[s,v,i]   (dense i 25)
  for (int idx = tid; idx < TSD * VDIM * VDIM; idx += 256) {
    int k = idx / (VDIM * VDIM);
    int r = (idx / VDIM) % VDIM;   // v (source, from x1)
    int q = idx % VDIM;            // i (dest, from x2)
    float adj = tanhf(x1l[k * VDIM + r] - x2l[k * VDIM + q]);
    rid += adj * adj;
    float wv = fmaf(adj, al, A[(s * VDIM + r) * VDIM + q]);
    ws[WBUF_OFF + (s * BDIM + b) * (TSD * VDIM * VDIM) + idx] = wv;
  }

  red[tid] = rid;
  __syncthreads();
  for (int st = 128; st > 0; st >>= 1) {
    if (tid < st) red[tid] += red[tid + st];
    __syncthreads();
  }
  if (tid == 0) out_ridge[s * BDIM + b] = red[0];

  if (b == 0) {  // W3^T: [s][c][o]
    for (int idx = tid; idx < ODIM * CDIM; idx += 256) {
      int o = idx / CDIM, c = idx % CDIM;
      ws[W3T_OFF + (s * CDIM + c) * ODIM + o] = W3[(s * ODIM + o) * CDIM + c];
    }
  }
}

// ---------------- Kernel 3: fused z -> (loss, y=BN(conv3)+x, relu) ----------------
// lanes = (c_l 8, i_l 8); per-wave i-group ibase = {0,8,16,17}; t in registers.
// xw layout: [v][c][t'20] XOR-swizzled by ((v&7)<<2); wl: [k][v][i25]; zl: [c][t][27]
__global__ __launch_bounds__(256, 3) void kmain(const float* __restrict__ x,
                                                const float* __restrict__ b3,
                                                const float* __restrict__ bng,
                                                const float* __restrict__ bnb,
                                                const float* __restrict__ bnm,
                                                const float* __restrict__ bnv,
                                                const float* __restrict__ ws,
                                                float* __restrict__ out,
                                                float* __restrict__ lossP) {
  const int tile = blockIdx.x;   // 0..31  (8 t per tile)
  const int b    = blockIdx.y;   // 0..31
  const int t0   = tile * 8;
  const int tid  = threadIdx.x;
  const int wid  = tid >> 6;
  const int lane = tid & 63;
  const int c_l  = lane >> 3;    // 0..7 (c within oct)
  const int i_l  = lane & 7;
  const int ibase = (wid < 3) ? wid * 8 : 17;
  const int i_g  = ibase + i_l;                  // 0..24
  const bool lmask = (wid < 3) || (i_l == 7);    // dedupe wave2/3 overlap for loss

  const int op = tid & 31;   // y-phase: owns o=op and o=op+32
  const int tq = tid >> 5;   // y-phase: t (0..7)
  const int sv = tid & 31, sc = tid >> 5;  // staging: v, c

  __shared__ __align__(16) float wl[TSD * VDIM * VDIM];  // 5625 fl, [k][v][i]
  __shared__ __align__(16) float xw[VDIM * 8 * 20];      // 4000 fl, [v][c][t'20] swizzled
  __shared__ __align__(16) float zl[8 * 8 * 27];         // 1728 fl, [c][t][27]
  __shared__ float red[256];

  float acc0[25], acc1[25];
#pragma unroll
  for (int i = 0; i < 25; ++i) { acc0[i] = 0.f; acc1[i] = 0.f; }

  const float* w3t = ws + W3T_OFF;

  for (int s = 0; s < 3; ++s) {
    // ---- stage w[s,b] into LDS (coalesced, linear) ----
    {
      const float* wsrc = ws + WBUF_OFF + (size_t)(s * BDIM + b) * (TSD * VDIM * VDIM);
      for (int idx = tid; idx < TSD * VDIM * VDIM; idx += 256) wl[idx] = wsrc[idx];
    }
    float lossS = 0.f;

    for (int oct = 0; oct < 8; ++oct) {
      // ---- stage x window: xw[v][c][tp] = x[b, oct*8+c, t0-8+tp, v], swizzled ----
      if (sv < VDIM) {
        const float* xsrc = x + (size_t)(b * 64 + oct * 8 + sc) * TDIM * VDIM + sv;
        const int sw = (sv & 7) << 2;
        const int base = sv * 160 + sc * 20;
#pragma unroll
        for (int tp = 0; tp < 16; ++tp) {
          int gt = t0 - 8 + tp;
          xw[(base + tp) ^ sw] = (gt >= 0) ? xsrc[(size_t)gt * VDIM] : 0.f;
        }
      }
      __syncthreads();   // SYNC1: wl + xw ready

      // ---- z-phase: lane (c_l, i_g) computes z[t] for t=0..7 ----
      float z[8];
#pragma unroll
      for (int t = 0; t < 8; ++t) z[t] = 0.f;

      for (int v = 0; v < VDIM; ++v) {
        const int sw = (v & 7) << 2;
        const int base = v * 160 + c_l * 20;
        float xv[16];
#pragma unroll
        for (int j = 0; j < 4; ++j) {
          float4 q = *(const float4*)&xw[(base + 4 * j) ^ sw];
          xv[4 * j + 0] = q.x; xv[4 * j + 1] = q.y;
          xv[4 * j + 2] = q.z; xv[4 * j + 3] = q.w;
        }
        const float* wp = &wl[v * VDIM + i_g];
#pragma unroll
        for (int k = 0; k < 9; ++k) {
          float wv = wp[k * (VDIM * VDIM)];
#pragma unroll
          for (int t = 0; t < 8; ++t) z[t] = fmaf(xv[k + t], wv, z[t]);
        }
      }

      // loss partial: (z - x[b,c,t0+t,i])^2
      {
        float lp = 0.f;
        const int swl = (i_g & 7) << 2;
        const int basel = i_g * 160 + c_l * 20 + 8;
#pragma unroll
        for (int t = 0; t < 8; ++t) {
          float d = z[t] - xw[(basel + t) ^ swl];
          lp = fmaf(d, d, lp);
        }
        if (lmask) lossS += lp;
      }

      // hand z to LDS
#pragma unroll
      for (int t = 0; t < 8; ++t) zl[(c_l * 8 + t) * 27 + i_g] = z[t];
      __syncthreads();   // SYNC2: zl ready; all xw/wl reads done

      // ---- y-phase: thread (op, tq) accumulates over this oct's 8 c's ----
      for (int cc = 0; cc < 8; ++cc) {
        int c = oct * 8 + cc;
        float w3a = w3t[(s * CDIM + c) * ODIM + op];
        float w3b = w3t[(s * CDIM + c) * ODIM + op + 32];
        const float* zp = &zl[(cc * 8 + tq) * 27];
#pragma unroll
        for (int i = 0; i < 25; ++i) {
          float zv = zp[i];
          acc0[i] = fmaf(w3a, zv, acc0[i]);
          acc1[i] = fmaf(w3b, zv, acc1[i]);
        }
      }
      __syncthreads();   // protect zl/xw before next oct's writes
    }

    // ---- loss reduce for this s ----
    red[tid] = lossS;
    __syncthreads();
    for (int st = 128; st > 0; st >>= 1) {
      if (tid < st) red[tid] += red[tid + st];
      __syncthreads();
    }
    if (tid == 0) lossP[(blockIdx.y * 32 + blockIdx.x) * 3 + s] = red[0];
    __syncthreads();   // red reuse safety for next s
  }

  // ---- epilogue: y = relu(BN(y + b3sum) + x) ----
  float b3s0 = b3[op] + b3[ODIM + op] + b3[2 * ODIM + op];
  float b3s1 = b3[op + 32] + b3[ODIM + op + 32] + b3[2 * ODIM + op + 32];
  float inv0 = bng[op] / sqrtf(bnv[op] + EPSV);
  float inv1 = bng[op + 32] / sqrtf(bnv[op + 32] + EPSV);
  float mu0 = bnm[op], mu1 = bnm[op + 32];
  float be0 = bnb[op], be1 = bnb[op + 32];

  {
    size_t r0 = ((size_t)(b * 64 + op) * TDIM + t0 + tq) * VDIM;
    size_t r1 = ((size_t)(b * 64 + op + 32) * TDIM + t0 + tq) * VDIM;
    const float* xr0 = x + r0;
    const float* xr1 = x + r1;
    float* yo0 = out + r0;
    float* yo1 = out + r1;
#pragma unroll
    for (int i = 0; i < VDIM; ++i) {
      float v0 = (acc0[i] + b3s0 - mu0) * inv0 + be0 + xr0[i];
      float v1 = (acc1[i] + b3s1 - mu1) * inv1 + be1 + xr1[i];
      yo0[i] = fmaxf(v0, 0.f);
      yo1[i] = fmaxf(v1, 0.f);
    }
  }
}

// ---------------- Kernel 4: finalize loss ----------------
__global__ __launch_bounds__(256) void kfin(const float* __restrict__ lossP,
                                            float* __restrict__ out_loss) {
  __shared__ float red[256];
  int tid = threadIdx.x;
  for (int s = 0; s < 3; ++s) {
    float a = 0.f;
    for (int i = tid; i < 1024; i += 256) a += lossP[i * 3 + s];
    red[tid] = a;
    __syncthreads();
    for (int st = 128; st > 0; st >>= 1) {
      if (tid < st) red[tid] += red[tid + st];
      __syncthreads();
    }
    if (tid == 0) out_loss[s] = red[0] * (1.f / 13107200.f);
    __syncthreads();
  }
}

extern "C" void kernel_launch(void* const* d_in, const int* in_sizes, int n_in,
                              void* d_out, int out_size, void* d_ws, size_t ws_size,
                              hipStream_t stream) {
  (void)in_sizes; (void)n_in; (void)out_size; (void)ws_size;
  const float* x     = (const float*)d_in[0];
  const float* A     = (const float*)d_in[1];
  const float* alpha = (const float*)d_in[2];
  const float* W1    = (const float*)d_in[3];
  const float* b1    = (const float*)d_in[4];
  const float* W2    = (const float*)d_in[5];
  const float* b2    = (const float*)d_in[6];
  const float* W3    = (const float*)d_in[7];
  const float* b3    = (const float*)d_in[8];
  const float* bng   = (const float*)d_in[9];
  const float* bnb   = (const float*)d_in[10];
  const float* bnm   = (const float*)d_in[11];
  const float* bnv   = (const float*)d_in[12];
  float* out = (float*)d_out;
  float* ws  = (float*)d_ws;
  float* out_loss  = out + 13107200;
  float* out_ridge = out + 13107203;
  float* lossP = ws + LOSSP_OFF;

  kmean<<<2048, 256, 0, stream>>>(x, ws);
  kadj<<<96, 256, 0, stream>>>(A, alpha, W1, b1, W2, b2, W3, ws, out_ridge);
  kmain<<<dim3(32, 32), 256, 0, stream>>>(x, b3, bng, bnb, bnm, bnv, ws, out, lossP);
  kfin<<<1, 256, 0, stream>>>(lossP, out_loss);
}

// Round 3
// 520.275 us; speedup vs baseline: 2.0592x; 1.1929x over previous
//
#include <hip/hip_runtime.h>
#include <hip/hip_bf16.h>

#define TDIM 256
#define VDIM 25
#define CDIM 64
#define BDIM 32
#define SDIM 3
#define TSD 9
#define ODIM 64
#define EPSV 1e-5f

// workspace layout
#define XM_OFF     0          // 51200 floats
#define W3T_OFF    51200      // 12288 floats
#define LOSSP_OFF  63488      // 3072 floats
#define WPACK_BYTE 266240     // shorts: 32 b * 3 s * 9216  (bf16 B-fragments)

typedef short s4v __attribute__((ext_vector_type(4)));
typedef float f4v __attribute__((ext_vector_type(4)));

__device__ __forceinline__ unsigned short f2bf(float f) {
  __hip_bfloat16 h = __float2bfloat16(f);
  return __builtin_bit_cast(unsigned short, h);
}
__device__ __forceinline__ float bf2f(unsigned short u) {
  unsigned v = ((unsigned)u) << 16;
  return __builtin_bit_cast(float, v);
}

// ---------------- Kernel 1: xm[b,c,v] = mean over T ----------------
__global__ __launch_bounds__(256) void kmean(const float* __restrict__ x,
                                             float* __restrict__ ws) {
  int bc = blockIdx.x;
  int tid = threadIdx.x;
  int vl = tid & 31, tr = tid >> 5;
  float acc = 0.f;
  if (vl < VDIM) {
    const float* p = x + (size_t)bc * TDIM * VDIM + vl;
    for (int t = tr; t < TDIM; t += 8) acc += p[(size_t)t * VDIM];
  }
  __shared__ float red[256];
  red[tid] = acc;
  __syncthreads();
  if (tr == 0 && vl < VDIM) {
    float s = 0.f;
    for (int r = 0; r < 8; ++r) s += red[r * 32 + vl];
    ws[XM_OFF + bc * VDIM + vl] = s * (1.f / 256.f);
  }
}

// ---------------- Kernel 2: dynamic weights -> packed bf16 B-frags ----------------
__global__ __launch_bounds__(256) void kadj(const float* __restrict__ A,
                                            const float* __restrict__ alpha,
                                            const float* __restrict__ W1,
                                            const float* __restrict__ b1,
                                            const float* __restrict__ W2,
                                            const float* __restrict__ b2,
                                            const float* __restrict__ W3,
                                            float* __restrict__ ws,
                                            float* __restrict__ out_ridge) {
  int s = blockIdx.x >> 5, b = blockIdx.x & 31;
  int tid = threadIdx.x;
  __shared__ float xm[CDIM * VDIM];
  __shared__ float w1l[TSD * CDIM], w2l[TSD * CDIM];
  __shared__ float b1l[TSD], b2l[TSD];
  __shared__ float x1l[TSD * VDIM], x2l[TSD * VDIM];
  __shared__ float red[256];
  __shared__ float wsm[TSD * VDIM * VDIM];   // w[k][v][i] f32

  for (int i = tid; i < CDIM * VDIM; i += 256) xm[i] = ws[XM_OFF + b * CDIM * VDIM + i];
  for (int i = tid; i < TSD * CDIM; i += 256) {
    w1l[i] = W1[s * TSD * CDIM + i];
    w2l[i] = W2[s * TSD * CDIM + i];
  }
  if (tid < TSD) { b1l[tid] = b1[s * TSD + tid]; b2l[tid] = b2[s * TSD + tid]; }
  __syncthreads();

  if (tid < TSD * VDIM) {
    int ts = tid / VDIM, v = tid % VDIM;
    float a1 = 0.f, a2 = 0.f;
    for (int c = 0; c < CDIM; ++c) {
      float xv = xm[c * VDIM + v];
      a1 = fmaf(xv, w1l[ts * CDIM + c], a1);
      a2 = fmaf(xv, w2l[ts * CDIM + c], a2);
    }
    x1l[tid] = a1 + b1l[ts];
    x2l[tid] = a2 + b2l[ts];
  }
  __syncthreads();

  float al = alpha[0];
  float rid = 0.f;
  for (int idx = tid; idx < TSD * VDIM * VDIM; idx += 256) {
    int k = idx / (VDIM * VDIM);
    int r = (idx / VDIM) % VDIM;   // v
    int q = idx % VDIM;            // i
    float adj = tanhf(x1l[k * VDIM + r] - x2l[k * VDIM + q]);
    rid += adj * adj;
    wsm[idx] = fmaf(adj, al, A[(s * VDIM + r) * VDIM + q]);
  }
  red[tid] = rid;
  __syncthreads();   // wsm + red complete

  // pack B-fragments: layout [tile=k*4+vh*2+n][i16][g4][j4], zero-padded
  {
    unsigned short* wp = (unsigned short*)((char*)ws + WPACK_BYTE)
                         + (size_t)(b * 3 + s) * 9216;
    for (int idx = tid; idx < 9216; idx += 256) {
      int tile = idx >> 8;
      int k = tile >> 2, vh = (tile >> 1) & 1, n = tile & 1;
      int e = idx & 255;
      int icol = e >> 4, gg = (e >> 2) & 3, jj = e & 3;
      int v = vh * 16 + gg * 4 + jj;
      int i = n * 16 + icol;
      float val = (v < VDIM && i < VDIM) ? wsm[k * (VDIM * VDIM) + v * VDIM + i] : 0.f;
      wp[idx] = f2bf(val);
    }
  }

  for (int st = 128; st > 0; st >>= 1) {
    if (tid < st) red[tid] += red[tid + st];
    __syncthreads();
  }
  if (tid == 0) out_ridge[s * BDIM + b] = red[0];

  if (b == 0) {  // W3^T: [s][c][o]
    for (int idx = tid; idx < ODIM * CDIM; idx += 256) {
      int o = idx / CDIM, c = idx % CDIM;
      ws[W3T_OFF + (s * CDIM + c) * ODIM + o] = W3[(s * ODIM + o) * CDIM + c];
    }
  }
}

// ---------------- Kernel 3: MFMA z -> (loss, y) ----------------
// Per block (b, t-tile 8). Wave wid owns c-pair cp=wid within each c-octet.
// z GEMM per (s,oct,wave): M=16 rows (cc2 x t8), N=2x16 (i), K=9k x 2vh x 16.
// A-frag: xw bf16 [c8][t'16][slot8][4v], slot rotated by (slot+t')&7.
// B-frag: wl bf16 [s][tile36][i16][g4][j4]  (pre-packed per-lane contiguous).
__global__ __launch_bounds__(256) void kmain(const float* __restrict__ x,
                                             const float* __restrict__ b3,
                                             const float* __restrict__ bng,
                                             const float* __restrict__ bnb,
                                             const float* __restrict__ bnm,
                                             const float* __restrict__ bnv,
                                             const float* __restrict__ ws,
                                             float* __restrict__ out,
                                             float* __restrict__ lossP) {
  const int tile = blockIdx.x;   // 0..31
  const int b    = blockIdx.y;   // 0..31
  const int t0   = tile * 8;
  const int tid  = threadIdx.x;
  const int wid  = tid >> 6;
  const int lane = tid & 63;

  __shared__ __align__(16) short wl[27648];     // 55296 B
  __shared__ __align__(16) short xw[4096];      // 8192 B
  __shared__ __align__(16) float zl[64 * 28];   // 7168 B
  __shared__ float red[256];

  // ---- copy packed w (all 3 s) for this b into LDS ----
  {
    const float4* src = (const float4*)((const char*)ws + WPACK_BYTE + (size_t)b * 55296);
    float4* dst = (float4*)wl;
    for (int i = tid; i < 3456; i += 256) dst[i] = src[i];
  }

  // lane constants
  const int cp    = wid;                 // c-pair within octet
  const int g     = lane >> 4;           // 0..3
  const int col   = lane & 15;           // A-row / B-col / C-col
  const int a_cc  = col >> 3;            // A: cc
  const int a_t   = col & 7;             // A: t
  const int abase = (cp * 2 + a_cc) * 16;

  const int op = tid & 31;               // y-phase o
  const int tq = tid >> 5;               // y-phase t
  const float* w3t = ws + W3T_OFF;

  float accA[25], accB[25];
#pragma unroll
  for (int i = 0; i < 25; ++i) { accA[i] = 0.f; accB[i] = 0.f; }
  float loss0 = 0.f, loss1 = 0.f, loss2 = 0.f;

  for (int oct = 0; oct < 8; ++oct) {
    // ---- stage x window bf16: xw[c][t'][slot'][4] ----
    {
      int c_s = tid >> 5, r = tid & 31;
      int slot = r & 7, t4 = r >> 3;
      const float* xsrc = x + (size_t)(b * 64 + oct * 8 + c_s) * TDIM * VDIM;
#pragma unroll
      for (int m = 0; m < 4; ++m) {
        int tp = m * 4 + t4;
        int gt = t0 - 8 + tp;
        int v0 = slot * 4;
        s4v pk;
#pragma unroll
        for (int jj = 0; jj < 4; ++jj) {
          float f = (gt >= 0 && (v0 + jj) < VDIM) ? xsrc[(size_t)gt * VDIM + v0 + jj] : 0.f;
          pk[jj] = (short)f2bf(f);
        }
        int sl = (slot + tp) & 7;
        *(s4v*)&xw[((c_s * 16 + tp) * 8 + sl) * 4] = pk;
      }
    }
    __syncthreads();   // xw (+ wl on first iter) ready

#pragma unroll
    for (int s = 0; s < 3; ++s) {
      const int sOff = s * 9216;
      // ---- z MFMA: 36 mfma_16x16x16_bf16 ----
      f4v acc0 = {0.f, 0.f, 0.f, 0.f};
      f4v acc1 = {0.f, 0.f, 0.f, 0.f};
#pragma unroll
      for (int k = 0; k < 9; ++k) {
        int tp = a_t + k;
#pragma unroll
        for (int vh = 0; vh < 2; ++vh) {
          int sl = (vh * 4 + g + tp) & 7;
          s4v av = *(const s4v*)&xw[((abase + tp) * 8 + sl) * 4];
          int tb = sOff + (k * 4 + vh * 2) * 256 + col * 16 + g * 4;
          s4v b0 = *(const s4v*)&wl[tb];
          s4v b1 = *(const s4v*)&wl[tb + 256];
          acc0 = __builtin_amdgcn_mfma_f32_16x16x16bf16_1k(av, b0, acc0, 0, 0, 0);
          acc1 = __builtin_amdgcn_mfma_f32_16x16x16bf16_1k(av, b1, acc1, 0, 0, 0);
        }
      }
      // ---- epilogue: loss + zl ----
      float lp = 0.f;
#pragma unroll
      for (int q = 0; q < 4; ++q) {
        int row = g * 4 + q;
        int cc2 = row >> 3, tt = row & 7;
        int cl = cp * 2 + cc2;
        int tp = tt + 8;
        {
          float zv = acc0[q];
          int sl = ((col >> 2) + tp) & 7;
          float xf = bf2f((unsigned short)xw[((cl * 16 + tp) * 8 + sl) * 4 + (col & 3)]);
          float d = zv - xf;
          lp = fmaf(d, d, lp);
          zl[(cl * 8 + tt) * 28 + col] = zv;
        }
        if (col < 9) {
          float zv = acc1[q];
          int i = 16 + col;
          int sl = ((i >> 2) + tp) & 7;
          float xf = bf2f((unsigned short)xw[((cl * 16 + tp) * 8 + sl) * 4 + (i & 3)]);
          float d = zv - xf;
          lp = fmaf(d, d, lp);
          zl[(cl * 8 + tt) * 28 + i] = zv;
        }
      }
      if (s == 0) loss0 += lp; else if (s == 1) loss1 += lp; else loss2 += lp;
      __syncthreads();   // zl ready

      // ---- y-phase: thread (op, tq), accumulate over this oct's 8 c ----
      for (int cc = 0; cc < 8; ++cc) {
        int c = oct * 8 + cc;
        float w3a = w3t[(s * CDIM + c) * ODIM + op];
        float w3b = w3t[(s * CDIM + c) * ODIM + op + 32];
        const float* zp = &zl[(cc * 8 + tq) * 28];
#pragma unroll
        for (int j4 = 0; j4 < 6; ++j4) {
          float4 zq = *(const float4*)&zp[j4 * 4];
          accA[j4 * 4 + 0] = fmaf(w3a, zq.x, accA[j4 * 4 + 0]);
          accA[j4 * 4 + 1] = fmaf(w3a, zq.y, accA[j4 * 4 + 1]);
          accA[j4 * 4 + 2] = fmaf(w3a, zq.z, accA[j4 * 4 + 2]);
          accA[j4 * 4 + 3] = fmaf(w3a, zq.w, accA[j4 * 4 + 3]);
          accB[j4 * 4 + 0] = fmaf(w3b, zq.x, accB[j4 * 4 + 0]);
          accB[j4 * 4 + 1] = fmaf(w3b, zq.y, accB[j4 * 4 + 1]);
          accB[j4 * 4 + 2] = fmaf(w3b, zq.z, accB[j4 * 4 + 2]);
          accB[j4 * 4 + 3] = fmaf(w3b, zq.w, accB[j4 * 4 + 3]);
        }
        float zlast = zp[24];
        accA[24] = fmaf(w3a, zlast, accA[24]);
        accB[24] = fmaf(w3b, zlast, accB[24]);
      }
      __syncthreads();   // zl reusable
    }
  }

  // ---- loss reduce ----
  {
    float lw[3] = {loss0, loss1, loss2};
#pragma unroll
    for (int s = 0; s < 3; ++s) {
      red[tid] = lw[s];
      __syncthreads();
      for (int st = 128; st > 0; st >>= 1) {
        if (tid < st) red[tid] += red[tid + st];
        __syncthreads();
      }
      if (tid == 0) lossP[(blockIdx.y * 32 + blockIdx.x) * 3 + s] = red[0];
      __syncthreads();
    }
  }

  // ---- epilogue: y = relu(BN(y + b3sum) + x) ----
  float b3s0 = b3[op] + b3[ODIM + op] + b3[2 * ODIM + op];
  float b3s1 = b3[op + 32] + b3[ODIM + op + 32] + b3[2 * ODIM + op + 32];
  float inv0 = bng[op] / sqrtf(bnv[op] + EPSV);
  float inv1 = bng[op + 32] / sqrtf(bnv[op + 32] + EPSV);
  float mu0 = bnm[op], mu1 = bnm[op + 32];
  float be0 = bnb[op], be1 = bnb[op + 32];
  {
    size_t r0 = ((size_t)(b * 64 + op) * TDIM + t0 + tq) * VDIM;
    size_t r1 = ((size_t)(b * 64 + op + 32) * TDIM + t0 + tq) * VDIM;
    const float* xr0 = x + r0;
    const float* xr1 = x + r1;
    float* yo0 = out + r0;
    float* yo1 = out + r1;
#pragma unroll
    for (int i = 0; i < VDIM; ++i) {
      float v0 = (accA[i] + b3s0 - mu0) * inv0 + be0 + xr0[i];
      float v1 = (accB[i] + b3s1 - mu1) * inv1 + be1 + xr1[i];
      yo0[i] = fmaxf(v0, 0.f);
      yo1[i] = fmaxf(v1, 0.f);
    }
  }
}

// ---------------- Kernel 4: finalize loss ----------------
__global__ __launch_bounds__(256) void kfin(const float* __restrict__ lossP,
                                            float* __restrict__ out_loss) {
  __shared__ float red[256];
  int tid = threadIdx.x;
  for (int s = 0; s < 3; ++s) {
    float a = 0.f;
    for (int i = tid; i < 1024; i += 256) a += lossP[i * 3 + s];
    red[tid] = a;
    __syncthreads();
    for (int st = 128; st > 0; st >>= 1) {
      if (tid < st) red[tid] += red[tid + st];
      __syncthreads();
    }
    if (tid == 0) out_loss[s] = red[0] * (1.f / 13107200.f);
    __syncthreads();
  }
}

extern "C" void kernel_launch(void* const* d_in, const int* in_sizes, int n_in,
                              void* d_out, int out_size, void* d_ws, size_t ws_size,
                              hipStream_t stream) {
  (void)in_sizes; (void)n_in; (void)out_size; (void)ws_size;
  const float* x     = (const float*)d_in[0];
  const float* A     = (const float*)d_in[1];
  const float* alpha = (const float*)d_in[2];
  const float* W1    = (const float*)d_in[3];
  const float* b1    = (const float*)d_in[4];
  const float* W2    = (const float*)d_in[5];
  const float* b2    = (const float*)d_in[6];
  const float* W3    = (const float*)d_in[7];
  const float* b3    = (const float*)d_in[8];
  const float* bng   = (const float*)d_in[9];
  const float* bnb   = (const float*)d_in[10];
  const float* bnm   = (const float*)d_in[11];
  const float* bnv   = (const float*)d_in[12];
  float* out = (float*)d_out;
  float* ws  = (float*)d_ws;
  float* out_loss  = out + 13107200;
  float* out_ridge = out + 13107203;
  float* lossP = ws + LOSSP_OFF;

  kmean<<<2048, 256, 0, stream>>>(x, ws);
  kadj<<<96, 256, 0, stream>>>(A, alpha, W1, b1, W2, b2, W3, ws, out_ridge);
  kmain<<<dim3(32, 32), 256, 0, stream>>>(x, b3, bng, bnb, bnm, bnv, ws, out, lossP);
  kfin<<<1, 256, 0, stream>>>(lossP, out_loss);
}

// Round 4
// 247.031 us; speedup vs baseline: 4.3370x; 2.1061x over previous
//
#include <hip/hip_runtime.h>
#include <hip/hip_bf16.h>

#define TDIM 256
#define VDIM 25
#define CDIM 64
#define BDIM 32
#define EPSV 1e-5f

// ws layout
#define XM_OFF     0            // 51200 floats
#define LOSSP_OFF  51200        // 3072 floats
#define WPACK_BYTE 217088       // 32b*3s*9792 shorts = 1880064 B (bf16 z B-frags)
#define WL_SH      9792         // shorts per (b,s): 18 kvh * 4 g * 136
#define W3P_BYTE   (WPACK_BYTE + 96 * WL_SH * 2)  // 2097152; 3s*4096 shorts

typedef short s4v __attribute__((ext_vector_type(4)));
typedef short s8v __attribute__((ext_vector_type(8)));
typedef float f4v __attribute__((ext_vector_type(4)));

__device__ __forceinline__ unsigned short f2bf(float f) {
  __hip_bfloat16 h = __float2bfloat16(f);
  return __builtin_bit_cast(unsigned short, h);
}
__device__ __forceinline__ float bf2f(unsigned short u) {
  unsigned v = ((unsigned)u) << 16;
  return __builtin_bit_cast(float, v);
}

// ---------------- Kernel 1: xm[b,c,v] = mean over T ----------------
__global__ __launch_bounds__(256) void kmean(const float* __restrict__ x,
                                             float* __restrict__ ws) {
  int bc = blockIdx.x;
  int tid = threadIdx.x;
  int vl = tid & 31, tr = tid >> 5;
  float acc = 0.f;
  if (vl < VDIM) {
    const float* p = x + (size_t)bc * TDIM * VDIM + vl;
    for (int t = tr; t < TDIM; t += 8) acc += p[(size_t)t * VDIM];
  }
  __shared__ float red[256];
  red[tid] = acc;
  __syncthreads();
  if (tr == 0 && vl < VDIM) {
    float s = 0.f;
    for (int r = 0; r < 8; ++r) s += red[r * 32 + vl];
    ws[XM_OFF + bc * VDIM + vl] = s * (1.f / 256.f);
  }
}

// ---------------- Kernel 2: dynamic weights -> packed bf16 fragments ----------------
__global__ __launch_bounds__(256) void kadj(const float* __restrict__ A,
                                            const float* __restrict__ alpha,
                                            const float* __restrict__ W1,
                                            const float* __restrict__ b1,
                                            const float* __restrict__ W2,
                                            const float* __restrict__ b2,
                                            const float* __restrict__ W3,
                                            float* __restrict__ ws,
                                            float* __restrict__ out_ridge) {
  int s = blockIdx.x >> 5, b = blockIdx.x & 31;
  int tid = threadIdx.x;
  __shared__ float xm[CDIM * VDIM];
  __shared__ float w1l[9 * CDIM], w2l[9 * CDIM];
  __shared__ float b1l[9], b2l[9];
  __shared__ float x1l[9 * VDIM], x2l[9 * VDIM];
  __shared__ float red[256];
  __shared__ float wsm[9 * VDIM * VDIM];   // w[k][v][i] f32

  for (int i = tid; i < CDIM * VDIM; i += 256) xm[i] = ws[XM_OFF + b * CDIM * VDIM + i];
  for (int i = tid; i < 9 * CDIM; i += 256) {
    w1l[i] = W1[s * 9 * CDIM + i];
    w2l[i] = W2[s * 9 * CDIM + i];
  }
  if (tid < 9) { b1l[tid] = b1[s * 9 + tid]; b2l[tid] = b2[s * 9 + tid]; }
  __syncthreads();

  if (tid < 9 * VDIM) {
    int ts = tid / VDIM, v = tid % VDIM;
    float a1 = 0.f, a2 = 0.f;
    for (int c = 0; c < CDIM; ++c) {
      float xv = xm[c * VDIM + v];
      a1 = fmaf(xv, w1l[ts * CDIM + c], a1);
      a2 = fmaf(xv, w2l[ts * CDIM + c], a2);
    }
    x1l[tid] = a1 + b1l[ts];
    x2l[tid] = a2 + b2l[ts];
  }
  __syncthreads();

  float al = alpha[0];
  float rid = 0.f;
  for (int idx = tid; idx < 9 * VDIM * VDIM; idx += 256) {
    int k = idx / (VDIM * VDIM);
    int r = (idx / VDIM) % VDIM;   // v
    int q = idx % VDIM;            // i
    float adj = tanhf(x1l[k * VDIM + r] - x2l[k * VDIM + q]);
    rid += adj * adj;
    wsm[idx] = fmaf(adj, al, A[(s * VDIM + r) * VDIM + q]);
  }
  red[tid] = rid;
  __syncthreads();   // wsm + red complete

  // pack z B-fragments: per (kvh,g) row of 136 shorts:
  //  col<8 at off=col*8, col>=8 at off=72+(col-8)*8; within: [n2][j4]
  {
    unsigned short* wp = (unsigned short*)((char*)ws + WPACK_BYTE) + (size_t)(b * 3 + s) * WL_SH;
    for (int idx = tid; idx < WL_SH; idx += 256) {
      int row = idx / 136;
      int off = idx - row * 136;
      float val = 0.f;
      int col = -1, rem = 0;
      if (off < 64) { col = off >> 3; rem = off & 7; }
      else if (off >= 72) { col = 8 + ((off - 72) >> 3); rem = (off - 72) & 7; }
      if (col >= 0) {
        int kvh = row >> 2, gg = row & 3;
        int k = kvh >> 1, vh = kvh & 1;
        int n = rem >> 2, jj = rem & 3;
        int v = vh * 16 + gg * 4 + jj;
        int i = n * 16 + col;
        if (v < VDIM && i < VDIM) val = wsm[(k * VDIM + v) * VDIM + i];
      }
      wp[idx] = f2bf(val);
    }
  }

  for (int st = 128; st > 0; st >>= 1) {
    if (tid < st) red[tid] += red[tid + st];
    __syncthreads();
  }
  if (tid == 0) out_ridge[s * BDIM + b] = red[0];

  // pack W3 A-frags: [s][p][mt][col16][g4][j4]; A[m=o][k=c_local], c = p*16+g*4+j
  if (b == 0) {
    unsigned short* w3p = (unsigned short*)((char*)ws + W3P_BYTE) + s * 4096;
    for (int idx = tid; idx < 4096; idx += 256) {
      int pm = idx >> 8;          // p*4+mt
      int p = pm >> 2, mt = pm & 3;
      int e = idx & 255;
      int colv = e >> 4, gg = (e >> 2) & 3, jj = e & 3;
      int o = mt * 16 + colv, c = p * 16 + gg * 4 + jj;
      w3p[idx] = f2bf(W3[(s * CDIM + o) * CDIM + c]);
    }
  }
}

// ---------------- Kernel 3: all-MFMA fused z -> (loss, y) ----------------
__global__ __launch_bounds__(256, 3) void kmain(const float* __restrict__ x,
                                                const float* __restrict__ b3,
                                                const float* __restrict__ bng,
                                                const float* __restrict__ bnb,
                                                const float* __restrict__ bnm,
                                                const float* __restrict__ bnv,
                                                const float* __restrict__ ws,
                                                float* __restrict__ out,
                                                float* __restrict__ lossP) {
  const int tile = blockIdx.x;   // 0..31 (8 t per tile)
  const int b    = blockIdx.y;   // 0..31
  const int t0   = tile * 8;
  const int tid  = threadIdx.x;
  const int wid  = tid >> 6;
  const int lane = tid & 63;
  const int g    = lane >> 4;
  const int col  = lane & 15;
  const int w4   = wid * 4;

  __shared__ __align__(16) short wl[WL_SH];   // 19584 B, z B-frags for one s
  __shared__ __align__(16) short xw[8704];    // 17408 B: 256 rows (16c x 16tp) x 17 uints
  __shared__ __align__(16) short zly[4608];   // 9216 B: [n 256][c16 pad18]
  __shared__ float bninv[64], bnoff[64];

  if (tid < 64) {
    float inv = bng[tid] / sqrtf(bnv[tid] + EPSV);
    bninv[tid] = inv;
    bnoff[tid] = (b3[tid] + b3[64 + tid] + b3[128 + tid] - bnm[tid]) * inv + bnb[tid];
  }

  const unsigned short* wpackb =
      (const unsigned short*)((const char*)ws + WPACK_BYTE) + (size_t)b * 3 * WL_SH;
  const unsigned short* w3p = (const unsigned short*)((const char*)ws + W3P_BYTE);

  auto stage_wl = [&](int s2) {
    const float4* src = (const float4*)(wpackb + (size_t)s2 * WL_SH);
    float4* dst = (float4*)wl;
    for (int i2 = tid; i2 < WL_SH / 8; i2 += 256) dst[i2] = src[i2];
  };
  auto stage_xw = [&](int p) {
    int c_s = tid >> 4, r = tid & 15;
    int slot = r & 7, th = r >> 3;
    const float* xsrc = x + (size_t)(b * 64 + p * 16 + c_s) * TDIM * VDIM;
    unsigned* xww = (unsigned*)xw;
#pragma unroll
    for (int m = 0; m < 8; ++m) {
      int tp = m * 2 + th;
      int gt = t0 - 8 + tp;
      float f0 = 0.f, f1 = 0.f, f2 = 0.f, f3 = 0.f;
      if (gt >= 0 && slot < 7) {
        const float* rp = xsrc + (size_t)gt * VDIM + slot * 4;
        if (slot < 6) { float4 q4 = *(const float4*)rp; f0 = q4.x; f1 = q4.y; f2 = q4.z; f3 = q4.w; }
        else f0 = rp[0];   // slot 6: only v=24 valid
      }
      unsigned lo = ((unsigned)f2bf(f0)) | (((unsigned)f2bf(f1)) << 16);
      unsigned hi = ((unsigned)f2bf(f2)) | (((unsigned)f2bf(f3)) << 16);
      int sl = (slot + tp) & 7;
      int o2 = (c_s * 16 + tp) * 17 + sl * 2;
      xww[o2] = lo; xww[o2 + 1] = hi;
    }
  };

  // z lane constants (A rows: m = (cl_local, t); cl = w4 + mt*2 + (col>>3), t = col&7)
  const int a_cc = col >> 3, a_t = col & 7;
  const int rowb0 = (w4 + a_cc) * 16 + a_t;
  const int rowb1 = (w4 + 2 + a_cc) * 16 + a_t;
  const int slb = g + a_t;
  const int wlOffB = g * 136 + col * 8 + (col >> 3) * 8;

  f4v yacc[4][4];
#pragma unroll
  for (int i = 0; i < 4; ++i)
#pragma unroll
    for (int j = 0; j < 4; ++j) yacc[i][j] = (f4v){0.f, 0.f, 0.f, 0.f};
  float lossA[3] = {0.f, 0.f, 0.f};

  stage_xw(0);
  stage_wl(0);

  for (int p = 0; p < 4; ++p) {
    for (int s = 0; s < 3; ++s) {
      // prefetch W3 A-frags (global, L2-hot)
      const unsigned short* a3p = w3p + (size_t)((s * 4 + p) * 4) * 256 + col * 16 + g * 4;
      s4v a3[4];
#pragma unroll
      for (int mt = 0; mt < 4; ++mt) a3[mt] = *(const s4v*)(a3p + mt * 256);

      __syncthreads();   // B1: xw + wl ready

      // ---- z MFMA: 72 mfma per wave ----
      f4v za[2][2];
#pragma unroll
      for (int i = 0; i < 2; ++i)
#pragma unroll
        for (int j = 0; j < 2; ++j) za[i][j] = (f4v){0.f, 0.f, 0.f, 0.f};
      const unsigned* xwu = (const unsigned*)xw;
#pragma unroll
      for (int k = 0; k < 9; ++k) {
#pragma unroll
        for (int vh = 0; vh < 2; ++vh) {
          int sl = (slb + vh * 4 + k) & 7;
          int off0 = (rowb0 + k) * 17 + sl * 2;
          int off1 = (rowb1 + k) * 17 + sl * 2;
          uint2 u0; u0.x = xwu[off0]; u0.y = xwu[off0 + 1];
          uint2 u1; u1.x = xwu[off1]; u1.y = xwu[off1 + 1];
          s4v a0 = __builtin_bit_cast(s4v, u0);
          s4v a1 = __builtin_bit_cast(s4v, u1);
          s8v bb = *(const s8v*)&wl[(k * 2 + vh) * 544 + wlOffB];
          s4v b0 = __builtin_shufflevector(bb, bb, 0, 1, 2, 3);
          s4v b1 = __builtin_shufflevector(bb, bb, 4, 5, 6, 7);
          za[0][0] = __builtin_amdgcn_mfma_f32_16x16x16bf16_1k(a0, b0, za[0][0], 0, 0, 0);
          za[0][1] = __builtin_amdgcn_mfma_f32_16x16x16bf16_1k(a0, b1, za[0][1], 0, 0, 0);
          za[1][0] = __builtin_amdgcn_mfma_f32_16x16x16bf16_1k(a1, b0, za[1][0], 0, 0, 0);
          za[1][1] = __builtin_amdgcn_mfma_f32_16x16x16bf16_1k(a1, b1, za[1][1], 0, 0, 0);
        }
      }

      // ---- loss + zly (bf16 B-frag layout [n][c]) ----
      float lp = 0.f;
#pragma unroll
      for (int mt = 0; mt < 2; ++mt) {
#pragma unroll
        for (int q = 0; q < 4; ++q) {
          int mrow = mt * 16 + g * 4 + q;
          int cl = w4 + (mrow >> 3);
          int t = mrow & 7;
          int tp = t + 8;
          int rowx = (cl * 16 + tp) * 34;
          {
            float zv = za[mt][0][q];
            int i = col;
            int sl2 = ((i >> 2) + tp) & 7;
            float xf = bf2f((unsigned short)xw[rowx + sl2 * 4 + (i & 3)]);
            float d = zv - xf;
            lp = fmaf(d, d, lp);
            zly[(t * 32 + i) * 18 + cl] = (short)f2bf(zv);
          }
          {
            float zv = za[mt][1][q];
            int i = 16 + col;
            zly[(t * 32 + i) * 18 + cl] = (short)f2bf(zv);
            if (i < VDIM) {
              int sl2 = ((i >> 2) + tp) & 7;
              float xf = bf2f((unsigned short)xw[rowx + sl2 * 4 + (i & 3)]);
              float d = zv - xf;
              lp = fmaf(d, d, lp);
            }
          }
        }
      }
      lossA[s] += lp;

      __syncthreads();   // B2: zly ready; xw/wl reads done

      // ---- y MFMA: 16 per wave; + stage next buffers in the shadow ----
      const unsigned* zlyu = (const unsigned*)zly;
#pragma unroll
      for (int nt = 0; nt < 4; ++nt) {
        int n = (w4 + nt) * 16 + col;
        int zo = n * 9 + g * 2;
        uint2 uz; uz.x = zlyu[zo]; uz.y = zlyu[zo + 1];
        s4v bz = __builtin_bit_cast(s4v, uz);
#pragma unroll
        for (int mt = 0; mt < 4; ++mt)
          yacc[mt][nt] = __builtin_amdgcn_mfma_f32_16x16x16bf16_1k(a3[mt], bz, yacc[mt][nt], 0, 0, 0);
      }
      if (s < 2) stage_wl(s + 1);
      else if (p < 3) { stage_wl(0); stage_xw(p + 1); }
    }
  }

  __syncthreads();
  // ---- loss reduce (reuse xw as scratch) ----
  {
    float* redf = (float*)xw;
#pragma unroll
    for (int s = 0; s < 3; ++s) {
      redf[tid] = lossA[s];
      __syncthreads();
      for (int st = 128; st > 0; st >>= 1) {
        if (tid < st) redf[tid] += redf[tid + st];
        __syncthreads();
      }
      if (tid == 0) lossP[(blockIdx.y * 32 + blockIdx.x) * 3 + s] = redf[0];
      __syncthreads();
    }
  }

  // ---- epilogue: y = relu(acc*inv + off + x) ----
#pragma unroll
  for (int nt = 0; nt < 4; ++nt) {
    int nIdx = (w4 + nt) * 16 + col;
    int t = nIdx >> 5, i = nIdx & 31;
    if (i < VDIM) {
      int gt = t0 + t;
#pragma unroll
      for (int mt = 0; mt < 4; ++mt) {
#pragma unroll
        for (int q = 0; q < 4; ++q) {
          int o = mt * 16 + g * 4 + q;
          size_t idx = ((size_t)(b * 64 + o) * TDIM + gt) * VDIM + i;
          float v = yacc[mt][nt][q] * bninv[o] + bnoff[o] + x[idx];
          out[idx] = fmaxf(v, 0.f);
        }
      }
    }
  }
}

// ---------------- Kernel 4: finalize loss ----------------
__global__ __launch_bounds__(256) void kfin(const float* __restrict__ lossP,
                                            float* __restrict__ out_loss) {
  __shared__ float red[256];
  int tid = threadIdx.x;
  for (int s = 0; s < 3; ++s) {
    float a = 0.f;
    for (int i = tid; i < 1024; i += 256) a += lossP[i * 3 + s];
    red[tid] = a;
    __syncthreads();
    for (int st = 128; st > 0; st >>= 1) {
      if (tid < st) red[tid] += red[tid + st];
      __syncthreads();
    }
    if (tid == 0) out_loss[s] = red[0] * (1.f / 13107200.f);
    __syncthreads();
  }
}

extern "C" void kernel_launch(void* const* d_in, const int* in_sizes, int n_in,
                              void* d_out, int out_size, void* d_ws, size_t ws_size,
                              hipStream_t stream) {
  (void)in_sizes; (void)n_in; (void)out_size; (void)ws_size;
  const float* x     = (const float*)d_in[0];
  const float* A     = (const float*)d_in[1];
  const float* alpha = (const float*)d_in[2];
  const float* W1    = (const float*)d_in[3];
  const float* b1    = (const float*)d_in[4];
  const float* W2    = (const float*)d_in[5];
  const float* b2    = (const float*)d_in[6];
  const float* W3    = (const float*)d_in[7];
  const float* b3    = (const float*)d_in[8];
  const float* bng   = (const float*)d_in[9];
  const float* bnb   = (const float*)d_in[10];
  const float* bnm   = (const float*)d_in[11];
  const float* bnv   = (const float*)d_in[12];
  float* out = (float*)d_out;
  float* ws  = (float*)d_ws;
  float* out_loss  = out + 13107200;
  float* out_ridge = out + 13107203;
  float* lossP = ws + LOSSP_OFF;

  kmean<<<2048, 256, 0, stream>>>(x, ws);
  kadj<<<96, 256, 0, stream>>>(A, alpha, W1, b1, W2, b2, W3, ws, out_ridge);
  kmain<<<dim3(32, 32), 256, 0, stream>>>(x, b3, bng, bnb, bnm, bnv, ws, out, lossP);
  kfin<<<1, 256, 0, stream>>>(lossP, out_loss);
}